// Round 9
// baseline (352.161 us; speedup 1.0000x reference)
//
#include <hip/hip_runtime.h>
#include <math.h>

#define N 6144
#define MAXD 128      // list capacity; deg clamped to 127 (7-bit counter planes)
#define NWORDS 96     // u64 words per row bitmap
#define NW32 192      // u32 words per row bitmap

typedef unsigned long long u64;
typedef unsigned int u32;
typedef unsigned char u8;

// full adder: (s, c) = a + b + ci
#define FA(s, c, a, b, ci) { u32 _t = (a) ^ (b); (s) = _t ^ (ci); (c) = ((a) & (b)) | ((ci) & _t); }

// inject one-bit plane cy into 7-plane counter p[] starting at plane START
template <int START>
__device__ __forceinline__ void badd_from(u32* p, u32 cy) {
    #pragma unroll
    for (int q = START; q < 6; ++q) { u32 x = p[q] & cy; p[q] ^= cy; cy = x; }
    p[6] ^= cy;
}

// add 15 one-bit words into 7-plane bit-sliced counter: 11 FA + 4 injections
__device__ __forceinline__ void csa15(u32* p, const u32* x) {
    u32 s0,c0,s1,c1,s2,c2,s3,c3,s4,c4;
    FA(s0,c0, x[0], x[1], x[2]);
    FA(s1,c1, x[3], x[4], x[5]);
    FA(s2,c2, x[6], x[7], x[8]);
    FA(s3,c3, x[9], x[10], x[11]);
    FA(s4,c4, x[12], x[13], x[14]);
    u32 t0,d0,u0,d1;
    FA(t0,d0, s0, s1, s2);
    FA(u0,d1, s3, s4, t0);          // u0 = weight-1 sum
    u32 e0,f0,e1,f1,e2,f2;
    FA(e0,f0, c0, c1, c2);
    FA(e1,f1, c3, c4, d0);
    FA(e2,f2, e0, e1, d1);          // e2 = weight-2 sum
    u32 g0,h0;
    FA(g0,h0, f0, f1, f2);          // g0 = weight-4, h0 = weight-8
    badd_from<0>(p, u0);
    badd_from<1>(p, e2);
    badd_from<2>(p, g0);
    badd_from<3>(p, h0);
}

// ---------------------------------------------------------------------------
// Kernel A: h = x @ W ;  Wh1 = h @ a[:64] ;  Wh2 = h @ a[64:]
// 32 rows/block (8 rows/wave); W staged once per block in LDS (64 KB).
// Also zeroes col_cnt (stream-ordered before k_build).
// ---------------------------------------------------------------------------
__global__ __launch_bounds__(256) void k_gemm_h(
    const float* __restrict__ x, const float* __restrict__ W,
    const float* __restrict__ a,
    float* __restrict__ h, float* __restrict__ Wh1, float* __restrict__ Wh2,
    int* __restrict__ col_cnt)
{
    int gid = blockIdx.x * 256 + threadIdx.x;
    if (gid < N) col_cnt[gid] = 0;

    __shared__ float Wl[256 * 64];
    int t = threadIdx.x;
    #pragma unroll
    for (int c = 0; c < 64; ++c) Wl[c * 256 + t] = W[c * 256 + t];
    __syncthreads();

    int w = t >> 6, lane = t & 63;
    int i0 = blockIdx.x * 32 + w * 8;
    const float* xr = x + (long)i0 * 256;

    float acc[8] = {0.f, 0.f, 0.f, 0.f, 0.f, 0.f, 0.f, 0.f};
    for (int k0 = 0; k0 < 256; k0 += 4) {
        float4 xv[8];
        #pragma unroll
        for (int r = 0; r < 8; ++r)
            xv[r] = *(const float4*)(xr + (long)r * 256 + k0);
        #pragma unroll
        for (int kk = 0; kk < 4; ++kk) {
            float wv = Wl[(k0 + kk) * 64 + lane];
            #pragma unroll
            for (int r = 0; r < 8; ++r) {
                float xs = (kk == 0) ? xv[r].x : (kk == 1) ? xv[r].y
                         : (kk == 2) ? xv[r].z : xv[r].w;
                acc[r] = fmaf(xs, wv, acc[r]);
            }
        }
    }

    #pragma unroll
    for (int r = 0; r < 8; ++r) {
        int i = i0 + r;
        h[(long)i * 64 + lane] = acc[r];
        float s1 = acc[r] * a[lane];
        float s2 = acc[r] * a[64 + lane];
        #pragma unroll
        for (int off = 32; off; off >>= 1) {
            s1 += __shfl_xor(s1, off, 64);
            s2 += __shfl_xor(s2, off, 64);
        }
        if (lane == 0) { Wh1[i] = s1; Wh2[i] = s2; }
    }
}

// ---------------------------------------------------------------------------
// Kernel B: block-per-row build of bitmap + CSR + CSC. Wave w owns columns
// [1536w, 1536w+1536): 24 loads ALL in flight (sched_barrier pins the batch
// so the compiler can't re-fuse phases and shrink the load window — R6 showed
// VGPR=20, i.e. ~2 loads in flight, without it), 24 ballots, one LDS atomic
// per wave reserving row-list slots, then independent scattered writes.
// ---------------------------------------------------------------------------
__global__ __launch_bounds__(256) void k_build(
    const float* __restrict__ adj,
    u64* __restrict__ rowbits, int* __restrict__ row_cnt, int* __restrict__ row_list,
    int* __restrict__ col_cnt, int* __restrict__ col_list)
{
    int i = blockIdx.x;
    int t = threadIdx.x, w = t >> 6, lane = t & 63;
    __shared__ int cnt;
    if (t == 0) cnt = 0;
    __syncthreads();

    const float* ar = adj + (long)i * N + w * 1536;

    // phase 1: all 24 loads issued before any consumer (pinned)
    float v[24];
    #pragma unroll
    for (int q = 0; q < 24; ++q)
        v[q] = __builtin_nontemporal_load(ar + q * 64 + lane);
    __builtin_amdgcn_sched_barrier(0);

    // phase 2: ballots
    u64 m[24];
    #pragma unroll
    for (int q = 0; q < 24; ++q) m[q] = __ballot(v[q] != 0.0f);

    // phase 3: wave-local total, single slot reservation
    int tot = 0;
    #pragma unroll
    for (int q = 0; q < 24; ++q) tot += __popcll(m[q]);
    int base = 0;
    if (lane == 0 && tot) base = atomicAdd(&cnt, tot);
    base = __shfl(base, 0, 64);

    // phase 4: bitmap stores + list writes (all independent)
    u64* rb = rowbits + (long)i * NWORDS + w * 24;
    #pragma unroll
    for (int q = 0; q < 24; ++q) {
        if (lane == 0) rb[q] = m[q];
        if ((m[q] >> lane) & 1ull) {
            int rank = __popcll(m[q] & ((1ull << lane) - 1ull));
            int s = base + rank;
            int j = w * 1536 + q * 64 + lane;
            if (s < MAXD) row_list[(long)i * MAXD + s] = j;
            int sc = atomicAdd(&col_cnt[j], 1);
            if (sc < MAXD) col_list[(long)j * MAXD + sc] = i;
        }
        base += __popcll(m[q]);     // wave-uniform running base
    }
    __syncthreads();
    if (t == 0) row_cnt[i] = cnt < 127 ? cnt : 127;   // clamp for 7-bit planes
}

// ---------------------------------------------------------------------------
// Kernel C (192 threads): per row i —
//   adj2 row counts: 15-way CSA tree over bitmap words, DOUBLE-BUFFERED
//   (batch m+1 loads issued & pinned before csa15 of batch m)
//   SWAR expansion to byte-packed LDS (conflict-free b32 writes)
//   a3 via 8-lane group per edge; softmax; h_prime = att @ h; elu
// ---------------------------------------------------------------------------
__global__ __launch_bounds__(192) void k_attn(
    const float* __restrict__ h, const float* __restrict__ Wh1, const float* __restrict__ Wh2,
    const u64* __restrict__ rowbits,
    const int* __restrict__ row_cnt, const int* __restrict__ row_list,
    const int* __restrict__ col_cnt, const int* __restrict__ col_list,
    const float* __restrict__ W_si, const float* __restrict__ W_ei,
    float* __restrict__ out)
{
    __shared__ u32 adj2p[8 * 256];   // byte-packed counts: col k -> byte (((k>>2)&7)<<10)+((k>>5)<<2)+(k&3); 8 KB
    __shared__ int nbr[MAXD];
    __shared__ int ccbuf[MAXD];
    __shared__ float lrbuf[MAXD];
    __shared__ float ebuf[MAXD];
    __shared__ float part[192];
    __shared__ float sh_max, sh_sum;

    int i = blockIdx.x;
    int t = threadIdx.x, w = t >> 6, lane = t & 63;
    int deg = row_cnt[i];
    deg = deg < 127 ? deg : 127;

    if (deg == 0) {
        float acc = 0.f;
        for (int r = w; r < N; r += 3) acc += h[(long)r * 64 + lane];
        part[t] = acc;
        __syncthreads();
        if (w == 0) {
            float s = part[lane] + part[64 + lane] + part[128 + lane];
            s *= (1.0f / N);
            out[(long)i * 64 + lane] = s > 0.f ? s : expm1f(s);
        }
        return;
    }

    float aWei = fabsf(W_ei[0]);
    float aWsi = fabsf(W_si[0]);

    // prologue: neighbor list + per-edge scalars (expansion barrier covers these)
    if (t < deg) {
        int j = row_list[(long)i * MAXD + t];
        nbr[t] = j;
        int cc = col_cnt[j];
        ccbuf[t] = cc < MAXD ? cc : MAXD;
        float z = Wh1[i] + Wh2[j];
        lrbuf[t] = aWei * (z > 0.f ? z : 0.2f * z);
    }

    // ---- adj2 accumulation: thread t owns u32 word t (cols 32t..32t+31)
    {
        const u32* rb32 = (const u32*)rowbits;
        const int* rl = row_list + (long)i * MAXD;   // uniform base -> s_load
        u32 p[7] = {0,0,0,0,0,0,0};

        int nbatch = deg / 15;                       // full batches
        u32 x[2][15];
        if (nbatch > 0) {
            #pragma unroll
            for (int q = 0; q < 15; ++q)
                x[0][q] = rb32[(long)rl[q] * NW32 + t];
            __builtin_amdgcn_sched_barrier(0);
        }
        for (int b = 0; b < nbatch; ++b) {
            int cur = b & 1, nxt = cur ^ 1;
            if (b + 1 < nbatch) {
                int m0 = (b + 1) * 15;
                #pragma unroll
                for (int q = 0; q < 15; ++q)
                    x[nxt][q] = rb32[(long)rl[m0 + q] * NW32 + t];
                __builtin_amdgcn_sched_barrier(0);
            }
            csa15(p, x[cur]);
        }
        int m = nbatch * 15;
        if (m < deg) {
            u32 xr[15];
            #pragma unroll
            for (int q = 0; q < 15; ++q) {
                int mq = m + q;
                int j = rl[mq < deg ? mq : 0];       // safe uniform index
                u32 vv = rb32[(long)j * NW32 + t];
                xr[q] = (mq < deg) ? vv : 0u;
            }
            csa15(p, xr);
        }

        // SWAR expansion: 4 cols/nibble -> 4 bytes; shift folded into constants
        #pragma unroll
        for (int g = 0; g < 8; ++g) {
            u32 acc = 0;
            #pragma unroll
            for (int pl = 0; pl < 7; ++pl) {
                u32 nib = (p[pl] >> (4 * g)) & 0xFu;
                acc += (nib * (0x00204081u << pl)) & (0x01010101u << pl);
            }
            adj2p[g * 256 + t] = acc;                // lane-consecutive, conflict-free
        }
    }
    __syncthreads();

    const u8* adj2b = (const u8*)adj2p;

    // ---- edge scores: 8-lane group per edge (24 groups across the block)
    {
        int g = t >> 3, sub = t & 7;
        for (int e = g; e < deg; e += 24) {
            int j = nbr[e];
            int cc = ccbuf[e];
            const int* cl = col_list + (long)j * MAXD;
            u32 a3 = 0;
            for (int q = sub; q < cc; q += 8) {
                int k = cl[q];
                a3 += (u32)adj2b[(((k >> 2) & 7) << 10) | (((k >> 5) << 2) | (k & 3))];
            }
            a3 += __shfl_xor(a3, 1, 64);
            a3 += __shfl_xor(a3, 2, 64);
            a3 += __shfl_xor(a3, 4, 64);
            if (sub == 0) {
                u32 a2 = (u32)adj2b[(((j >> 2) & 7) << 10) | (((j >> 5) << 2) | (j & 3))];
                ebuf[e] = lrbuf[e] + aWsi * (float)(1u + a2 + a3);
            }
        }
    }
    __syncthreads();

    // ---- softmax over deg neighbors (wave 0)
    if (w == 0) {
        float v = -3.4e38f;
        for (int idx = lane; idx < deg; idx += 64) v = fmaxf(v, ebuf[idx]);
        #pragma unroll
        for (int off = 32; off; off >>= 1) v = fmaxf(v, __shfl_xor(v, off, 64));
        if (lane == 0) sh_max = v;
    }
    __syncthreads();
    if (t < deg) ebuf[t] = expf(ebuf[t] - sh_max);
    __syncthreads();
    if (w == 0) {
        float s = 0.f;
        for (int idx = lane; idx < deg; idx += 64) s += ebuf[idx];
        #pragma unroll
        for (int off = 32; off; off >>= 1) s += __shfl_xor(s, off, 64);
        if (lane == 0) sh_sum = s;
    }
    __syncthreads();

    // ---- h_prime[i, lane] = (1/sum) * sum_e p_e * h[nbr[e], lane]
    float accf = 0.f;
    for (int e = w; e < deg; e += 3)
        accf = fmaf(ebuf[e], h[(long)nbr[e] * 64 + lane], accf);
    part[t] = accf;
    __syncthreads();
    if (w == 0) {
        float s = part[lane] + part[64 + lane] + part[128 + lane];
        s /= sh_sum;
        out[(long)i * 64 + lane] = s > 0.f ? s : expm1f(s);
    }
}

// ---------------------------------------------------------------------------
extern "C" void kernel_launch(void* const* d_in, const int* in_sizes, int n_in,
                              void* d_out, int out_size, void* d_ws, size_t ws_size,
                              hipStream_t stream) {
    const float* x    = (const float*)d_in[0];
    const float* adj  = (const float*)d_in[1];
    const float* W    = (const float*)d_in[2];
    const float* a    = (const float*)d_in[3];
    const float* W_si = (const float*)d_in[4];
    const float* W_ei = (const float*)d_in[5];
    float* out = (float*)d_out;

    char* ws = (char*)d_ws;
    size_t off = 0;
    auto alloc = [&](size_t bytes) -> void* {
        void* p = ws + off;
        off += (bytes + 255) & ~(size_t)255;
        return p;
    };
    u64*   rowbits  = (u64*)  alloc((size_t)N * NWORDS * sizeof(u64));   // 4.72 MB
    float* h        = (float*)alloc((size_t)N * 64 * sizeof(float));     // 1.57 MB
    float* Wh1      = (float*)alloc((size_t)N * sizeof(float));
    float* Wh2      = (float*)alloc((size_t)N * sizeof(float));
    int*   row_cnt  = (int*)  alloc((size_t)N * sizeof(int));
    int*   row_list = (int*)  alloc((size_t)N * MAXD * sizeof(int));     // 3.15 MB
    int*   col_cnt  = (int*)  alloc((size_t)N * sizeof(int));
    int*   col_list = (int*)  alloc((size_t)N * MAXD * sizeof(int));     // 3.15 MB

    k_gemm_h<<<N / 32, 256, 0, stream>>>(x, W, a, h, Wh1, Wh2, col_cnt);
    k_build <<<N, 256, 0, stream>>>(adj, rowbits, row_cnt, row_list, col_cnt, col_list);
    k_attn  <<<N, 192, 0, stream>>>(h, Wh1, Wh2, rowbits, row_cnt, row_list,
                                    col_cnt, col_list, W_si, W_ei, out);
}

// Round 10
// 323.664 us; speedup vs baseline: 1.0880x; 1.0880x over previous
//
#include <hip/hip_runtime.h>
#include <math.h>

#define N 6144
#define MAXD 128      // list capacity; deg clamped to 127 (7-bit counter planes)
#define NWORDS 96    // u64 words per row bitmap
#define NW32 192      // u32 words per row bitmap

typedef unsigned long long u64;
typedef unsigned int u32;
typedef unsigned char u8;

// full adder: (s, c) = a + b + ci
#define FA(s, c, a, b, ci) { u32 _t = (a) ^ (b); (s) = _t ^ (ci); (c) = ((a) & (b)) | ((ci) & _t); }

// inject one-bit plane cy into 7-plane counter p[] starting at plane START
template <int START>
__device__ __forceinline__ void badd_from(u32* p, u32 cy) {
    #pragma unroll
    for (int q = START; q < 6; ++q) { u32 x = p[q] & cy; p[q] ^= cy; cy = x; }
    p[6] ^= cy;
}

// add 15 one-bit words into 7-plane bit-sliced counter: 11 FA + 4 injections
__device__ __forceinline__ void csa15(u32* p, const u32* x) {
    u32 s0,c0,s1,c1,s2,c2,s3,c3,s4,c4;
    FA(s0,c0, x[0], x[1], x[2]);
    FA(s1,c1, x[3], x[4], x[5]);
    FA(s2,c2, x[6], x[7], x[8]);
    FA(s3,c3, x[9], x[10], x[11]);
    FA(s4,c4, x[12], x[13], x[14]);
    u32 t0,d0,u0,d1;
    FA(t0,d0, s0, s1, s2);
    FA(u0,d1, s3, s4, t0);          // u0 = weight-1 sum
    u32 e0,f0,e1,f1,e2,f2;
    FA(e0,f0, c0, c1, c2);
    FA(e1,f1, c3, c4, d0);
    FA(e2,f2, e0, e1, d1);          // e2 = weight-2 sum
    u32 g0,h0;
    FA(g0,h0, f0, f1, f2);          // g0 = weight-4, h0 = weight-8
    badd_from<0>(p, u0);
    badd_from<1>(p, e2);
    badd_from<2>(p, g0);
    badd_from<3>(p, h0);
}

// ---------------------------------------------------------------------------
// Kernel A: h = x @ W ;  Wh1 = h @ a[:64] ;  Wh2 = h @ a[64:]
// 32 rows/block (8 rows/wave); W staged once per block in LDS (64 KB).
// Also zeroes col_cnt (stream-ordered before k_build).
// ---------------------------------------------------------------------------
__global__ __launch_bounds__(256) void k_gemm_h(
    const float* __restrict__ x, const float* __restrict__ W,
    const float* __restrict__ a,
    float* __restrict__ h, float* __restrict__ Wh1, float* __restrict__ Wh2,
    int* __restrict__ col_cnt)
{
    int gid = blockIdx.x * 256 + threadIdx.x;
    if (gid < N) col_cnt[gid] = 0;

    __shared__ float Wl[256 * 64];
    int t = threadIdx.x;
    #pragma unroll
    for (int c = 0; c < 64; ++c) Wl[c * 256 + t] = W[c * 256 + t];
    __syncthreads();

    int w = t >> 6, lane = t & 63;
    int i0 = blockIdx.x * 32 + w * 8;
    const float* xr = x + (long)i0 * 256;

    float acc[8] = {0.f, 0.f, 0.f, 0.f, 0.f, 0.f, 0.f, 0.f};
    for (int k0 = 0; k0 < 256; k0 += 4) {
        float4 xv[8];
        #pragma unroll
        for (int r = 0; r < 8; ++r)
            xv[r] = *(const float4*)(xr + (long)r * 256 + k0);
        #pragma unroll
        for (int kk = 0; kk < 4; ++kk) {
            float wv = Wl[(k0 + kk) * 64 + lane];
            #pragma unroll
            for (int r = 0; r < 8; ++r) {
                float xs = (kk == 0) ? xv[r].x : (kk == 1) ? xv[r].y
                         : (kk == 2) ? xv[r].z : xv[r].w;
                acc[r] = fmaf(xs, wv, acc[r]);
            }
        }
    }

    #pragma unroll
    for (int r = 0; r < 8; ++r) {
        int i = i0 + r;
        h[(long)i * 64 + lane] = acc[r];
        float s1 = acc[r] * a[lane];
        float s2 = acc[r] * a[64 + lane];
        #pragma unroll
        for (int off = 32; off; off >>= 1) {
            s1 += __shfl_xor(s1, off, 64);
            s2 += __shfl_xor(s2, off, 64);
        }
        if (lane == 0) { Wh1[i] = s1; Wh2[i] = s2; }
    }
}

// ---------------------------------------------------------------------------
// Kernel B: row bitsets + CSR row lists + CSC column lists
// two-phase: 24 loads in flight, then ballots / list building
// (R5 configuration — measured best; sched_barrier variants regressed)
// ---------------------------------------------------------------------------
__global__ __launch_bounds__(256) void k_build(
    const float* __restrict__ adj,
    u64* __restrict__ rowbits, int* __restrict__ row_cnt, int* __restrict__ row_list,
    int* __restrict__ col_cnt, int* __restrict__ col_list)
{
    int i = blockIdx.x;
    int t = threadIdx.x, w = t >> 6, lane = t & 63;
    __shared__ int cnt;
    if (t == 0) cnt = 0;
    __syncthreads();

    const float* ar = adj + (long)i * N;

    float v[24];
    #pragma unroll
    for (int c = 0; c < 24; ++c)
        v[c] = __builtin_nontemporal_load(ar + c * 256 + t);

    u64 mask[24];
    #pragma unroll
    for (int c = 0; c < 24; ++c) mask[c] = __ballot(v[c] != 0.0f);

    #pragma unroll
    for (int c = 0; c < 24; ++c) {
        if (lane == 0) rowbits[(long)i * NWORDS + c * 4 + w] = mask[c];
        int base = 0;
        if (lane == 0 && mask[c]) base = atomicAdd(&cnt, __popcll(mask[c]));
        base = __shfl(base, 0, 64);
        if ((mask[c] >> lane) & 1ull) {
            int rank = __popcll(mask[c] & ((1ull << lane) - 1ull));
            int s = base + rank;
            int j = c * 256 + t;
            if (s < MAXD) row_list[(long)i * MAXD + s] = j;
            int sc = atomicAdd(&col_cnt[j], 1);
            if (sc < MAXD) col_list[(long)j * MAXD + sc] = i;
        }
    }
    __syncthreads();
    if (t == 0) row_cnt[i] = cnt < 127 ? cnt : 127;   // clamp for 7-bit planes
}

// ---------------------------------------------------------------------------
// Kernel C (192 threads): per row i —
//   adj2 row counts: 15-way CSA tree over bitmap words (scalar-loaded
//   neighbor indices, coalesced word loads, 7 bit-planes in regs)
//   SWAR expansion to byte-packed LDS (conflict-free b32 writes)
//   a3 via 8-lane group per edge; softmax; h_prime = att @ h (2 acc chains); elu
// ---------------------------------------------------------------------------
__global__ __launch_bounds__(192) void k_attn(
    const float* __restrict__ h, const float* __restrict__ Wh1, const float* __restrict__ Wh2,
    const u64* __restrict__ rowbits,
    const int* __restrict__ row_cnt, const int* __restrict__ row_list,
    const int* __restrict__ col_cnt, const int* __restrict__ col_list,
    const float* __restrict__ W_si, const float* __restrict__ W_ei,
    float* __restrict__ out)
{
    __shared__ u32 adj2p[8 * 256];   // byte-packed counts: col k -> byte (((k>>2)&7)<<10)+((k>>5)<<2)+(k&3); 8 KB
    __shared__ int nbr[MAXD];
    __shared__ int ccbuf[MAXD];
    __shared__ float lrbuf[MAXD];
    __shared__ float ebuf[MAXD];
    __shared__ float part[192];
    __shared__ float sh_max, sh_sum;

    int i = blockIdx.x;
    int t = threadIdx.x, w = t >> 6, lane = t & 63;
    int deg = row_cnt[i];
    deg = deg < 127 ? deg : 127;

    if (deg == 0) {
        float acc = 0.f;
        for (int r = w; r < N; r += 3) acc += h[(long)r * 64 + lane];
        part[t] = acc;
        __syncthreads();
        if (w == 0) {
            float s = part[lane] + part[64 + lane] + part[128 + lane];
            s *= (1.0f / N);
            out[(long)i * 64 + lane] = s > 0.f ? s : expm1f(s);
        }
        return;
    }

    float aWei = fabsf(W_ei[0]);
    float aWsi = fabsf(W_si[0]);

    // prologue: neighbor list + per-edge scalars (expansion barrier covers these)
    if (t < deg) {
        int j = row_list[(long)i * MAXD + t];
        nbr[t] = j;
        int cc = col_cnt[j];
        ccbuf[t] = cc < MAXD ? cc : MAXD;
        float z = Wh1[i] + Wh2[j];
        lrbuf[t] = aWei * (z > 0.f ? z : 0.2f * z);
    }

    // ---- adj2 accumulation: thread t owns u32 word t (cols 32t..32t+31)
    {
        const u32* rb32 = (const u32*)rowbits;
        const int* rl = row_list + (long)i * MAXD;   // uniform base -> s_load
        u32 p[7] = {0,0,0,0,0,0,0};

        int m = 0;
        for (; m + 15 <= deg; m += 15) {
            u32 x[15];
            #pragma unroll
            for (int q = 0; q < 15; ++q) {
                int j = rl[m + q];                   // wave-uniform -> scalar load
                x[q] = rb32[(long)j * NW32 + t];
            }
            csa15(p, x);
        }
        if (m < deg) {
            u32 x[15];
            #pragma unroll
            for (int q = 0; q < 15; ++q) {
                int mq = m + q;
                int j = rl[mq < deg ? mq : 0];       // safe uniform index
                u32 vv = rb32[(long)j * NW32 + t];
                x[q] = (mq < deg) ? vv : 0u;
            }
            csa15(p, x);
        }

        // SWAR expansion: 4 cols/nibble -> 4 bytes; shift folded into constants
        #pragma unroll
        for (int g = 0; g < 8; ++g) {
            u32 acc = 0;
            #pragma unroll
            for (int pl = 0; pl < 7; ++pl) {
                u32 nib = (p[pl] >> (4 * g)) & 0xFu;
                acc += (nib * (0x00204081u << pl)) & (0x01010101u << pl);
            }
            adj2p[g * 256 + t] = acc;                // lane-consecutive, conflict-free
        }
    }
    __syncthreads();

    const u8* adj2b = (const u8*)adj2p;

    // ---- edge scores: 8-lane group per edge (24 groups across the block)
    {
        int g = t >> 3, sub = t & 7;
        for (int e = g; e < deg; e += 24) {
            int j = nbr[e];
            int cc = ccbuf[e];
            const int* cl = col_list + (long)j * MAXD;
            u32 a3 = 0;
            for (int q = sub; q < cc; q += 8) {
                int k = cl[q];
                a3 += (u32)adj2b[(((k >> 2) & 7) << 10) | (((k >> 5) << 2) | (k & 3))];
            }
            a3 += __shfl_xor(a3, 1, 64);
            a3 += __shfl_xor(a3, 2, 64);
            a3 += __shfl_xor(a3, 4, 64);
            if (sub == 0) {
                u32 a2 = (u32)adj2b[(((j >> 2) & 7) << 10) | (((j >> 5) << 2) | (j & 3))];
                ebuf[e] = lrbuf[e] + aWsi * (float)(1u + a2 + a3);
            }
        }
    }
    __syncthreads();

    // ---- softmax over deg neighbors (wave 0)
    if (w == 0) {
        float v = -3.4e38f;
        for (int idx = lane; idx < deg; idx += 64) v = fmaxf(v, ebuf[idx]);
        #pragma unroll
        for (int off = 32; off; off >>= 1) v = fmaxf(v, __shfl_xor(v, off, 64));
        if (lane == 0) sh_max = v;
    }
    __syncthreads();
    if (t < deg) ebuf[t] = expf(ebuf[t] - sh_max);
    __syncthreads();
    if (w == 0) {
        float s = 0.f;
        for (int idx = lane; idx < deg; idx += 64) s += ebuf[idx];
        #pragma unroll
        for (int off = 32; off; off >>= 1) s += __shfl_xor(s, off, 64);
        if (lane == 0) sh_sum = s;
    }
    __syncthreads();

    // ---- h_prime[i, lane] = (1/sum) * sum_e p_e * h[nbr[e], lane]
    //      two independent accumulator chains -> 2 h-row loads in flight
    float acc0 = 0.f, acc1 = 0.f;
    int e = w;
    for (; e + 3 < deg; e += 6) {
        acc0 = fmaf(ebuf[e],     h[(long)nbr[e]     * 64 + lane], acc0);
        acc1 = fmaf(ebuf[e + 3], h[(long)nbr[e + 3] * 64 + lane], acc1);
    }
    if (e < deg)
        acc0 = fmaf(ebuf[e], h[(long)nbr[e] * 64 + lane], acc0);
    part[t] = acc0 + acc1;
    __syncthreads();
    if (w == 0) {
        float s = part[lane] + part[64 + lane] + part[128 + lane];
        s /= sh_sum;
        out[(long)i * 64 + lane] = s > 0.f ? s : expm1f(s);
    }
}

// ---------------------------------------------------------------------------
extern "C" void kernel_launch(void* const* d_in, const int* in_sizes, int n_in,
                              void* d_out, int out_size, void* d_ws, size_t ws_size,
                              hipStream_t stream) {
    const float* x    = (const float*)d_in[0];
    const float* adj  = (const float*)d_in[1];
    const float* W    = (const float*)d_in[2];
    const float* a    = (const float*)d_in[3];
    const float* W_si = (const float*)d_in[4];
    const float* W_ei = (const float*)d_in[5];
    float* out = (float*)d_out;

    char* ws = (char*)d_ws;
    size_t off = 0;
    auto alloc = [&](size_t bytes) -> void* {
        void* p = ws + off;
        off += (bytes + 255) & ~(size_t)255;
        return p;
    };
    u64*   rowbits  = (u64*)  alloc((size_t)N * NWORDS * sizeof(u64));   // 4.72 MB
    float* h        = (float*)alloc((size_t)N * 64 * sizeof(float));     // 1.57 MB
    float* Wh1      = (float*)alloc((size_t)N * sizeof(float));
    float* Wh2      = (float*)alloc((size_t)N * sizeof(float));
    int*   row_cnt  = (int*)  alloc((size_t)N * sizeof(int));
    int*   row_list = (int*)  alloc((size_t)N * MAXD * sizeof(int));     // 3.15 MB
    int*   col_cnt  = (int*)  alloc((size_t)N * sizeof(int));
    int*   col_list = (int*)  alloc((size_t)N * MAXD * sizeof(int));     // 3.15 MB

    k_gemm_h<<<N / 32, 256, 0, stream>>>(x, W, a, h, Wh1, Wh2, col_cnt);
    k_build <<<N, 256, 0, stream>>>(adj, rowbits, row_cnt, row_list, col_cnt, col_list);
    k_attn  <<<N, 192, 0, stream>>>(h, Wh1, Wh2, rowbits, row_cnt, row_list,
                                    col_cnt, col_list, W_si, W_ei, out);
}